// Round 17
// baseline (283.938 us; speedup 1.0000x reference)
//
#include <hip/hip_runtime.h>
#include <math.h>

#define T_TOK 8192
#define DIMX 1024
#define NE 8
#define HID 2048
#define NPAIR (T_TOK * 2)
#define P_PAD (NPAIR + NE * 128)
#define GATE_TPB 32

typedef __attribute__((ext_vector_type(8))) short s16x8;
typedef __attribute__((ext_vector_type(4))) float f32x4;

static __device__ __forceinline__ unsigned short f2bf(float f) {
    union { float f; unsigned u; } v; v.f = f;
    unsigned r = v.u + 0x7FFFu + ((v.u >> 16) & 1u);
    return (unsigned short)(r >> 16);
}
static __device__ __forceinline__ float bf2f(unsigned short u) {
    union { unsigned u; float f; } v; v.u = (unsigned)u << 16; return v.f;
}

// gelu tanh approximation: v * sigmoid(1.5957691 * v * (1 + 0.044715 v^2))
static __device__ __forceinline__ float gelu_fast(float v) {
    float u2 = -1.5957691216057308f * v * (1.f + 0.044715f * v * v);
    return v * __builtin_amdgcn_rcpf(1.f + __expf(u2));
}

// async global->LDS, 16 bytes per lane. LDS dest must be wave-uniform base + lane*16.
static __device__ __forceinline__ void gload16(const unsigned short* g, unsigned short* l) {
    __builtin_amdgcn_global_load_lds(
        (const __attribute__((address_space(1))) unsigned int*)g,
        (__attribute__((address_space(3))) unsigned int*)l, 16, 0, 0);
}

// ---------------- init: routing slots + counts ----------------
__global__ void init_routing_kernel(int* slot_token, float* slot_weight, int* counts) {
    int i = blockIdx.x * blockDim.x + threadIdx.x;
    if (i < P_PAD) { slot_token[i] = 0; slot_weight[i] = 0.f; }
    if (i < NE) counts[i] = 0;
}

// fused transpose of both weight tensors: z<8 -> W1 [1024][2048], else W2 [2048][1024]
// src [E][R][C] fp32 -> dst [E][C][R] bf16, 64x64 tiles, vectorized both sides
__global__ __launch_bounds__(256) void conv_transpose2_kernel(
    const float* __restrict__ W1, const float* __restrict__ W2,
    unsigned short* __restrict__ W1t, unsigned short* __restrict__ W2t) {
    __shared__ float tile[64][65];
    int z = blockIdx.z;
    int e = z & 7;
    const float* srcb; unsigned short* dstb; int R, C;
    if (z < 8) { srcb = W1; dstb = W1t; R = DIMX; C = HID; }
    else       { srcb = W2; dstb = W2t; R = HID; C = DIMX; }
    int r0 = blockIdx.y * 64, c0 = blockIdx.x * 64;
    if (r0 >= R || c0 >= C) return;
    const float* s = srcb + (size_t)e * R * C;
    unsigned short* d = dstb + (size_t)e * R * C;
    int tid = threadIdx.x;
    int lr = tid >> 4, lc4 = (tid & 15) * 4;  // 16 rows per pass x 16 float4
    #pragma unroll
    for (int it = 0; it < 4; it++) {
        float4 v = *(const float4*)&s[(size_t)(r0 + it * 16 + lr) * C + c0 + lc4];
        tile[it * 16 + lr][lc4 + 0] = v.x;
        tile[it * 16 + lr][lc4 + 1] = v.y;
        tile[it * 16 + lr][lc4 + 2] = v.z;
        tile[it * 16 + lr][lc4 + 3] = v.w;
    }
    __syncthreads();
    int cc = tid >> 3, rch = (tid & 7) * 8;  // 32 dst rows per pass x 8 chunks of 8
    #pragma unroll
    for (int it = 0; it < 2; it++) {
        int c = it * 32 + cc;
        unsigned short r[8];
        #pragma unroll
        for (int j = 0; j < 8; j++) r[j] = f2bf(tile[rch + j][c]);
        *(uint4*)&d[(size_t)(c0 + c) * R + r0 + rch] = *(const uint4*)&r[0];
    }
}

// ---------------- gating: block-aggregated atomics; also emits xb (bf16 x) ----------------
__global__ __launch_bounds__(256) void gate_kernel(
    const float* __restrict__ x, const float* __restrict__ gw, const float* __restrict__ gb,
    float* __restrict__ logits_out, int* counts, int* __restrict__ pair_epos,
    float* __restrict__ pair_w, unsigned short* __restrict__ xb) {
    __shared__ float sgw[NE * DIMX];
    __shared__ int lcount[NE], lbase[NE];
    __shared__ int s_e[GATE_TPB * 2];
    __shared__ int s_lp[GATE_TPB * 2];
    __shared__ float s_wv[GATE_TPB * 2];
    int tid = threadIdx.x;
    for (int i = tid; i < NE * DIMX / 4; i += 256)
        ((float4*)sgw)[i] = ((const float4*)gw)[i];
    if (tid < NE) lcount[tid] = 0;
    __syncthreads();

    int wave = tid >> 6, lane = tid & 63;
    int tbase = blockIdx.x * GATE_TPB;
    for (int r = 0; r < GATE_TPB / 4; ++r) {
        int ti = wave * (GATE_TPB / 4) + r;
        int t = tbase + ti;
        const float* xr = x + (size_t)t * DIMX;
        float acc[NE] = {};
        #pragma unroll
        for (int i = 0; i < DIMX / 256; i++) {
            float4 xv = *(const float4*)&xr[i * 256 + lane * 4];
            // fold convx: emit bf16 copy of x while it's in registers
            unsigned short rb[4] = { f2bf(xv.x), f2bf(xv.y), f2bf(xv.z), f2bf(xv.w) };
            *(uint2*)&xb[(size_t)t * DIMX + i * 256 + lane * 4] = *(const uint2*)&rb[0];
            #pragma unroll
            for (int e = 0; e < NE; e++) {
                float4 wv = *(const float4*)&sgw[e * DIMX + i * 256 + lane * 4];
                acc[e] += xv.x * wv.x + xv.y * wv.y + xv.z * wv.z + xv.w * wv.w;
            }
        }
        #pragma unroll
        for (int e = 0; e < NE; e++) {
            #pragma unroll
            for (int off = 32; off; off >>= 1) acc[e] += __shfl_xor(acc[e], off);
        }
        if (lane == 0) {
            float* lo = logits_out + (size_t)t * NE;
            #pragma unroll
            for (int e = 0; e < NE; e++) { acc[e] += gb[e]; lo[e] = acc[e]; }
            // top-2 (strict > keeps lowest index on ties, matching jax.lax.top_k)
            float l0 = acc[0]; int e0 = 0;
            #pragma unroll
            for (int e = 1; e < NE; e++) if (acc[e] > l0) { l0 = acc[e]; e0 = e; }
            float l1 = -1e30f; int e1 = -1;
            #pragma unroll
            for (int e = 0; e < NE; e++) if (e != e0 && acc[e] > l1) { l1 = acc[e]; e1 = e; }
            float q = expf(l1 - l0);
            float wn0 = 1.f / (1.f + q);
            float wn1 = q / (1.f + q);
            int lp0 = atomicAdd(&lcount[e0], 1);
            int lp1 = atomicAdd(&lcount[e1], 1);
            s_e[ti * 2] = e0; s_lp[ti * 2] = lp0; s_wv[ti * 2] = wn0;
            s_e[ti * 2 + 1] = e1; s_lp[ti * 2 + 1] = lp1; s_wv[ti * 2 + 1] = wn1;
        }
    }
    __syncthreads();
    if (tid < NE) lbase[tid] = atomicAdd(&counts[tid], lcount[tid]);
    __syncthreads();
    if (tid < GATE_TPB * 2) {
        int e = s_e[tid];
        int gp = lbase[e] + s_lp[tid];
        int gi = (tbase + (tid >> 1)) * 2 + (tid & 1);
        pair_epos[gi] = (e << 28) | gp;
        pair_w[gi] = s_wv[tid];
    }
}

__global__ void scan_kernel(const int* counts, int* offsets) {
    if (threadIdx.x == 0 && blockIdx.x == 0) {
        int o = 0;
        offsets[0] = 0;
        for (int e = 0; e < NE; e++) { o += (counts[e] + 127) & ~127; offsets[e + 1] = o; }
    }
}

__global__ void place_kernel(const int* __restrict__ pair_epos, const float* __restrict__ pair_w,
                             const int* __restrict__ offsets, int* __restrict__ slot_token,
                             float* __restrict__ slot_weight, int* __restrict__ tok2slot) {
    int p = blockIdx.x * 256 + threadIdx.x;
    if (p >= NPAIR) return;
    int ep = pair_epos[p];
    int e = ep >> 28;
    int pos = ep & 0x0FFFFFFF;
    int slot = offsets[e] + pos;
    slot_token[slot] = p >> 1;
    slot_weight[slot] = pair_w[p];
    tok2slot[p] = slot;
}

// pipeline: 2-buffer LDS, BK=64, depth-1 prefetch, counted vmcnt, raw barriers.
#define BARRIER() asm volatile("s_barrier" ::: "memory")
#define WAIT_VM(n) asm volatile("s_waitcnt vmcnt(" #n ")" ::: "memory")
#define WAIT_LGKM0() do { asm volatile("s_waitcnt lgkmcnt(0)" ::: "memory"); \
                          __builtin_amdgcn_sched_barrier(0); } while (0)

// Swizzled LDS tile layout, 1024 chunks of 16B per 128x64 tile:
//   slot c holds global chunk (row = c>>3, kseg = (c&7) ^ (row&7)).
// Write: 8 threads per row cover the row's contiguous 128B (permuted) -> coalesced;
//   256 threads x 4 chunks (rows tid>>3 + {0,32,64,96}, kperm invariant mod 32).
// Read: fragment (row, kseg = kk*4+lg) at slot row*8 + (kseg ^ (row&7));
//   kx = (kk*4+lg) ^ (lr&7): any aligned 8-lane window hits all 8 bank-groups once.
// Geometry: 256 thr / 4 waves (2m x 2n), 128x128 tile, per-wave 64x64 (4m x 4n):
//   16 ds_read_b128 -> 32 MFMA per BK=64 iter = 500 B/MFMA (vs R16's 750),
//   acc[4][4] = 64 AGPR, LDS 64KB -> 2 blocks/CU (8 waves/CU).

// ---------------- grouped GEMM 1: h = gelu(x @ W1 + b1) ----------------
// grid (8=expert, HID/128, 128): expert on blockIdx.x pins expert e -> XCD e (flat%8).
__global__ __launch_bounds__(256, 2) void gemm1_kernel(
    const unsigned short* __restrict__ xb, const unsigned short* __restrict__ W1t,
    const float* __restrict__ b1, const int* __restrict__ offsets,
    const int* __restrict__ slot_token, unsigned short* __restrict__ hbuf) {
    int e = blockIdx.x;
    int row_base = offsets[e];
    int rows = offsets[e + 1] - row_base;
    int m0 = blockIdx.z * 128;
    if (m0 >= rows) return;
    int n0 = blockIdx.y * 128;

    __shared__ unsigned short sA[2][128 * 64];
    __shared__ unsigned short sB[2][128 * 64];

    int tid = threadIdx.x;
    const unsigned short* w1e = W1t + (size_t)e * HID * DIMX;

    int srow = tid >> 3;                       // 0..31
    int kperm = (tid & 7) ^ (srow & 7);
    int tok0 = slot_token[row_base + m0 + srow];
    int tok1 = slot_token[row_base + m0 + srow + 32];
    int tok2 = slot_token[row_base + m0 + srow + 64];
    int tok3 = slot_token[row_base + m0 + srow + 96];
    const unsigned short* gA0 = xb + (size_t)tok0 * DIMX + kperm * 8;
    const unsigned short* gA1 = xb + (size_t)tok1 * DIMX + kperm * 8;
    const unsigned short* gA2 = xb + (size_t)tok2 * DIMX + kperm * 8;
    const unsigned short* gA3 = xb + (size_t)tok3 * DIMX + kperm * 8;
    const unsigned short* gB0 = w1e + (size_t)(n0 + srow) * DIMX + kperm * 8;
    const unsigned short* gB1 = w1e + (size_t)(n0 + srow + 32) * DIMX + kperm * 8;
    const unsigned short* gB2 = w1e + (size_t)(n0 + srow + 64) * DIMX + kperm * 8;
    const unsigned short* gB3 = w1e + (size_t)(n0 + srow + 96) * DIMX + kperm * 8;

#define STG1(b, k0) do { \
        gload16(gA0 + (k0), &sA[b][tid * 8]); \
        gload16(gA1 + (k0), &sA[b][(tid + 256) * 8]); \
        gload16(gA2 + (k0), &sA[b][(tid + 512) * 8]); \
        gload16(gA3 + (k0), &sA[b][(tid + 768) * 8]); \
        gload16(gB0 + (k0), &sB[b][tid * 8]); \
        gload16(gB1 + (k0), &sB[b][(tid + 256) * 8]); \
        gload16(gB2 + (k0), &sB[b][(tid + 512) * 8]); \
        gload16(gB3 + (k0), &sB[b][(tid + 768) * 8]); \
    } while (0)

    f32x4 acc[4][4] = {};
    int wid = tid >> 6; int wr = wid >> 1, wc = wid & 1;   // 2m x 2n waves
    int lane = tid & 63; int lr = lane & 15, lg = lane >> 4;
    int kx0 = lg ^ (lr & 7);                   // k-subtile 0; subtile 1 = kx0^4

#define CMP1(CUR) do { \
        _Pragma("unroll") \
        for (int kk = 0; kk < 2; kk++) { \
            int kxo = (kx0 ^ (kk * 4)) * 8; \
            s16x8 af[4], bfr[4]; \
            _Pragma("unroll") \
            for (int m = 0; m < 4; m++) af[m] = *(const s16x8*)&sA[CUR][(wr * 64 + m * 16 + lr) * 64 + kxo]; \
            _Pragma("unroll") \
            for (int n = 0; n < 4; n++) bfr[n] = *(const s16x8*)&sB[CUR][(wc * 64 + n * 16 + lr) * 64 + kxo]; \
            __builtin_amdgcn_s_setprio(1); \
            _Pragma("unroll") \
            for (int m = 0; m < 4; m++) { \
                _Pragma("unroll") \
                for (int n = 0; n < 4; n++) \
                    acc[m][n] = __builtin_amdgcn_mfma_f32_16x16x32_bf16(af[m], bfr[n], acc[m][n], 0, 0, 0); \
            } \
            __builtin_amdgcn_s_setprio(0); \
        } \
    } while (0)

    const int NT = DIMX / 64;
    STG1(0, 0);
    int cur = 0;
    for (int t = 0; t < NT - 1; ++t) {
        STG1(cur ^ 1, (t + 1) * 64);
        WAIT_VM(8);       // my 8 loads for tile t done; t+1's stay in flight
        BARRIER();
        CMP1(cur);
        WAIT_LGKM0();
        BARRIER();
        cur ^= 1;
    }
    WAIT_VM(0);
    BARRIER();
    CMP1(cur);
#undef STG1
#undef CMP1

    #pragma unroll
    for (int n = 0; n < 4; n++) {
        int col = n0 + wc * 64 + n * 16 + lr;
        float bias = b1[e * HID + col];
        #pragma unroll
        for (int m = 0; m < 4; m++) {
            #pragma unroll
            for (int i = 0; i < 4; i++) {
                int row = wr * 64 + m * 16 + lg * 4 + i;
                float v = gelu_fast(acc[m][n][i] + bias);
                hbuf[(size_t)(row_base + m0 + row) * HID + col] = f2bf(v);
            }
        }
    }
}

// ---------------- grouped GEMM 2: ybuf[slot] = w * (h @ W2 + b2), plain stores ----------------
__global__ __launch_bounds__(256, 2) void gemm2_kernel(
    const unsigned short* __restrict__ hbuf, const unsigned short* __restrict__ W2t,
    const float* __restrict__ b2, const int* __restrict__ offsets,
    const float* __restrict__ slot_weight, unsigned short* __restrict__ ybuf) {
    int e = blockIdx.x;
    int row_base = offsets[e];
    int rows = offsets[e + 1] - row_base;
    int m0 = blockIdx.z * 128;
    if (m0 >= rows) return;
    int n0 = blockIdx.y * 128;

    __shared__ unsigned short sA[2][128 * 64];
    __shared__ unsigned short sB[2][128 * 64];
    __shared__ float s_w[128];

    int tid = threadIdx.x;
    if (tid < 128) s_w[tid] = slot_weight[row_base + m0 + tid];

    const unsigned short* ha = hbuf + (size_t)(row_base + m0) * HID;
    const unsigned short* w2e = W2t + (size_t)e * DIMX * HID;

    int srow = tid >> 3;
    int kperm = (tid & 7) ^ (srow & 7);
    const unsigned short* gA0 = ha + (size_t)srow * HID + kperm * 8;
    const unsigned short* gA1 = ha + (size_t)(srow + 32) * HID + kperm * 8;
    const unsigned short* gA2 = ha + (size_t)(srow + 64) * HID + kperm * 8;
    const unsigned short* gA3 = ha + (size_t)(srow + 96) * HID + kperm * 8;
    const unsigned short* gB0 = w2e + (size_t)(n0 + srow) * HID + kperm * 8;
    const unsigned short* gB1 = w2e + (size_t)(n0 + srow + 32) * HID + kperm * 8;
    const unsigned short* gB2 = w2e + (size_t)(n0 + srow + 64) * HID + kperm * 8;
    const unsigned short* gB3 = w2e + (size_t)(n0 + srow + 96) * HID + kperm * 8;

#define STG2(b, k0) do { \
        gload16(gA0 + (k0), &sA[b][tid * 8]); \
        gload16(gA1 + (k0), &sA[b][(tid + 256) * 8]); \
        gload16(gA2 + (k0), &sA[b][(tid + 512) * 8]); \
        gload16(gA3 + (k0), &sA[b][(tid + 768) * 8]); \
        gload16(gB0 + (k0), &sB[b][tid * 8]); \
        gload16(gB1 + (k0), &sB[b][(tid + 256) * 8]); \
        gload16(gB2 + (k0), &sB[b][(tid + 512) * 8]); \
        gload16(gB3 + (k0), &sB[b][(tid + 768) * 8]); \
    } while (0)

    f32x4 acc[4][4] = {};
    int wid = tid >> 6; int wr = wid >> 1, wc = wid & 1;
    int lane = tid & 63; int lr = lane & 15, lg = lane >> 4;
    int kx0 = lg ^ (lr & 7);

#define CMP2(CUR) do { \
        _Pragma("unroll") \
        for (int kk = 0; kk < 2; kk++) { \
            int kxo = (kx0 ^ (kk * 4)) * 8; \
            s16x8 af[4], bfr[4]; \
            _Pragma("unroll") \
            for (int m = 0; m < 4; m++) af[m] = *(const s16x8*)&sA[CUR][(wr * 64 + m * 16 + lr) * 64 + kxo]; \
            _Pragma("unroll") \
            for (int n = 0; n < 4; n++) bfr[n] = *(const s16x8*)&sB[CUR][(wc * 64 + n * 16 + lr) * 64 + kxo]; \
            __builtin_amdgcn_s_setprio(1); \
            _Pragma("unroll") \
            for (int m = 0; m < 4; m++) { \
                _Pragma("unroll") \
                for (int n = 0; n < 4; n++) \
                    acc[m][n] = __builtin_amdgcn_mfma_f32_16x16x32_bf16(af[m], bfr[n], acc[m][n], 0, 0, 0); \
            } \
            __builtin_amdgcn_s_setprio(0); \
        } \
    } while (0)

    const int NT = HID / 64;
    STG2(0, 0);
    int cur = 0;
    for (int t = 0; t < NT - 1; ++t) {
        STG2(cur ^ 1, (t + 1) * 64);
        WAIT_VM(8);
        BARRIER();
        CMP2(cur);
        WAIT_LGKM0();
        BARRIER();
        cur ^= 1;
    }
    WAIT_VM(0);
    BARRIER();
    CMP2(cur);
#undef STG2
#undef CMP2

    #pragma unroll
    for (int n = 0; n < 4; n++) {
        int col = n0 + wc * 64 + n * 16 + lr;
        float bias = b2[e * DIMX + col];
        #pragma unroll
        for (int m = 0; m < 4; m++) {
            #pragma unroll
            for (int i = 0; i < 4; i++) {
                int row = wr * 64 + m * 16 + lg * 4 + i;
                float v = (acc[m][n][i] + bias) * s_w[row];
                ybuf[(size_t)(row_base + m0 + row) * DIMX + col] = f2bf(v);
            }
        }
    }
}

// ---------------- combine: out[t] = ybuf[slotA] + ybuf[slotB] ----------------
__global__ __launch_bounds__(256) void combine_kernel(
    const unsigned short* __restrict__ ybuf, const int* __restrict__ tok2slot,
    float* __restrict__ out) {
    int t = blockIdx.x;
    int d = threadIdx.x * 4;
    int sa = tok2slot[t * 2], sb = tok2slot[t * 2 + 1];
    ushort4 a = *(const ushort4*)&ybuf[(size_t)sa * DIMX + d];
    ushort4 b = *(const ushort4*)&ybuf[(size_t)sb * DIMX + d];
    float4 o;
    o.x = bf2f(a.x) + bf2f(b.x);
    o.y = bf2f(a.y) + bf2f(b.y);
    o.z = bf2f(a.z) + bf2f(b.z);
    o.w = bf2f(a.w) + bf2f(b.w);
    *(float4*)&out[(size_t)t * DIMX + d] = o;
}

extern "C" void kernel_launch(void* const* d_in, const int* in_sizes, int n_in,
                              void* d_out, int out_size, void* d_ws, size_t ws_size,
                              hipStream_t stream) {
    const float* x  = (const float*)d_in[0];
    const float* gw = (const float*)d_in[1];
    const float* gb = (const float*)d_in[2];
    const float* W1 = (const float*)d_in[3];
    const float* b1 = (const float*)d_in[4];
    const float* W2 = (const float*)d_in[5];
    const float* b2 = (const float*)d_in[6];
    float* out = (float*)d_out;
    float* logits = out + (size_t)T_TOK * DIMX;

    char* ws = (char*)d_ws;
    unsigned short* W2t = (unsigned short*)ws; ws += (size_t)NE * DIMX * HID * 2;
    // ybuf (P_PAD x DIMX bf16 = 35.7 MB) overlays [W1t | xb] (48 MB), both dead after gemm1.
    unsigned short* W1t = (unsigned short*)ws;
    unsigned short* ybuf = (unsigned short*)ws; ws += (size_t)NE * DIMX * HID * 2;
    unsigned short* xb = (unsigned short*)ws; ws += (size_t)T_TOK * DIMX * 2;
    unsigned short* hbuf = (unsigned short*)ws; ws += (size_t)P_PAD * HID * 2;
    int* counts = (int*)ws; ws += 256;
    int* offsets = (int*)ws; ws += 256;
    int* pair_epos = (int*)ws; ws += (size_t)NPAIR * 4;
    float* pair_w = (float*)ws; ws += (size_t)NPAIR * 4;
    int* slot_token = (int*)ws; ws += (size_t)P_PAD * 4;
    float* slot_weight = (float*)ws; ws += (size_t)P_PAD * 4;
    int* tok2slot = (int*)ws; ws += (size_t)NPAIR * 4;

    init_routing_kernel<<<(P_PAD + 255) / 256, 256, 0, stream>>>(slot_token, slot_weight, counts);
    conv_transpose2_kernel<<<dim3(32, 32, 16), 256, 0, stream>>>(W1, W2, W1t, W2t);
    gate_kernel<<<T_TOK / GATE_TPB, 256, 0, stream>>>(x, gw, gb, logits, counts, pair_epos,
                                                      pair_w, xb);
    scan_kernel<<<1, 1, 0, stream>>>(counts, offsets);
    place_kernel<<<NPAIR / 256, 256, 0, stream>>>(pair_epos, pair_w, offsets, slot_token,
                                                  slot_weight, tok2slot);
    // expert on blockIdx.x (gridDim.x=8): flat_id % 8 == expert -> one XCD per expert.
    gemm1_kernel<<<dim3(NE, HID / 128, 128), 256, 0, stream>>>(xb, W1t, b1, offsets, slot_token, hbuf);
    gemm2_kernel<<<dim3(NE, DIMX / 128, 128), 256, 0, stream>>>(hbuf, W2t, b2, offsets, slot_weight, ybuf);
    combine_kernel<<<T_TOK, 256, 0, stream>>>(ybuf, tok2slot, out);
}

// Round 18
// 268.047 us; speedup vs baseline: 1.0593x; 1.0593x over previous
//
#include <hip/hip_runtime.h>
#include <math.h>

#define T_TOK 8192
#define DIMX 1024
#define NE 8
#define HID 2048
#define NPAIR (T_TOK * 2)
#define P_PAD (NPAIR + NE * 128)
#define GATE_TPB 32

typedef __attribute__((ext_vector_type(8))) short s16x8;
typedef __attribute__((ext_vector_type(4))) float f32x4;

static __device__ __forceinline__ unsigned short f2bf(float f) {
    union { float f; unsigned u; } v; v.f = f;
    unsigned r = v.u + 0x7FFFu + ((v.u >> 16) & 1u);
    return (unsigned short)(r >> 16);
}
static __device__ __forceinline__ float bf2f(unsigned short u) {
    union { unsigned u; float f; } v; v.u = (unsigned)u << 16; return v.f;
}

// gelu tanh approximation: v * sigmoid(1.5957691 * v * (1 + 0.044715 v^2))
static __device__ __forceinline__ float gelu_fast(float v) {
    float u2 = -1.5957691216057308f * v * (1.f + 0.044715f * v * v);
    return v * __builtin_amdgcn_rcpf(1.f + __expf(u2));
}

// async global->LDS, 16 bytes per lane. LDS dest must be wave-uniform base + lane*16.
static __device__ __forceinline__ void gload16(const unsigned short* g, unsigned short* l) {
    __builtin_amdgcn_global_load_lds(
        (const __attribute__((address_space(1))) unsigned int*)g,
        (__attribute__((address_space(3))) unsigned int*)l, 16, 0, 0);
}

// fused transpose of both weight tensors: z<8 -> W1 [1024][2048], else W2 [2048][1024]
// src [E][R][C] fp32 -> dst [E][C][R] bf16, 64x64 tiles, vectorized both sides.
// Also zeroes the gate's counts[] (block (0,0,0)) -- runs before gate.
__global__ __launch_bounds__(256) void conv_transpose2_kernel(
    const float* __restrict__ W1, const float* __restrict__ W2,
    unsigned short* __restrict__ W1t, unsigned short* __restrict__ W2t, int* counts) {
    __shared__ float tile[64][65];
    int z = blockIdx.z;
    int e = z & 7;
    if (z == 0 && blockIdx.x == 0 && blockIdx.y == 0 && threadIdx.x < NE)
        counts[threadIdx.x] = 0;
    const float* srcb; unsigned short* dstb; int R, C;
    if (z < 8) { srcb = W1; dstb = W1t; R = DIMX; C = HID; }
    else       { srcb = W2; dstb = W2t; R = HID; C = DIMX; }
    int r0 = blockIdx.y * 64, c0 = blockIdx.x * 64;
    if (r0 >= R || c0 >= C) return;
    const float* s = srcb + (size_t)e * R * C;
    unsigned short* d = dstb + (size_t)e * R * C;
    int tid = threadIdx.x;
    int lr = tid >> 4, lc4 = (tid & 15) * 4;  // 16 rows per pass x 16 float4
    #pragma unroll
    for (int it = 0; it < 4; it++) {
        float4 v = *(const float4*)&s[(size_t)(r0 + it * 16 + lr) * C + c0 + lc4];
        tile[it * 16 + lr][lc4 + 0] = v.x;
        tile[it * 16 + lr][lc4 + 1] = v.y;
        tile[it * 16 + lr][lc4 + 2] = v.z;
        tile[it * 16 + lr][lc4 + 3] = v.w;
    }
    __syncthreads();
    int cc = tid >> 3, rch = (tid & 7) * 8;  // 32 dst rows per pass x 8 chunks of 8
    #pragma unroll
    for (int it = 0; it < 2; it++) {
        int c = it * 32 + cc;
        unsigned short r[8];
        #pragma unroll
        for (int j = 0; j < 8; j++) r[j] = f2bf(tile[rch + j][c]);
        *(uint4*)&d[(size_t)(c0 + c) * R + r0 + rch] = *(const uint4*)&r[0];
    }
}

// ---------------- gating: block-aggregated atomics; also emits xb (bf16 x) ----------------
__global__ __launch_bounds__(256) void gate_kernel(
    const float* __restrict__ x, const float* __restrict__ gw, const float* __restrict__ gb,
    float* __restrict__ logits_out, int* counts, int* __restrict__ pair_epos,
    float* __restrict__ pair_w, unsigned short* __restrict__ xb) {
    __shared__ float sgw[NE * DIMX];
    __shared__ int lcount[NE], lbase[NE];
    __shared__ int s_e[GATE_TPB * 2];
    __shared__ int s_lp[GATE_TPB * 2];
    __shared__ float s_wv[GATE_TPB * 2];
    int tid = threadIdx.x;
    for (int i = tid; i < NE * DIMX / 4; i += 256)
        ((float4*)sgw)[i] = ((const float4*)gw)[i];
    if (tid < NE) lcount[tid] = 0;
    __syncthreads();

    int wave = tid >> 6, lane = tid & 63;
    int tbase = blockIdx.x * GATE_TPB;
    for (int r = 0; r < GATE_TPB / 4; ++r) {
        int ti = wave * (GATE_TPB / 4) + r;
        int t = tbase + ti;
        const float* xr = x + (size_t)t * DIMX;
        float acc[NE] = {};
        #pragma unroll
        for (int i = 0; i < DIMX / 256; i++) {
            float4 xv = *(const float4*)&xr[i * 256 + lane * 4];
            // fold convx: emit bf16 copy of x while it's in registers
            unsigned short rb[4] = { f2bf(xv.x), f2bf(xv.y), f2bf(xv.z), f2bf(xv.w) };
            *(uint2*)&xb[(size_t)t * DIMX + i * 256 + lane * 4] = *(const uint2*)&rb[0];
            #pragma unroll
            for (int e = 0; e < NE; e++) {
                float4 wv = *(const float4*)&sgw[e * DIMX + i * 256 + lane * 4];
                acc[e] += xv.x * wv.x + xv.y * wv.y + xv.z * wv.z + xv.w * wv.w;
            }
        }
        #pragma unroll
        for (int e = 0; e < NE; e++) {
            #pragma unroll
            for (int off = 32; off; off >>= 1) acc[e] += __shfl_xor(acc[e], off);
        }
        if (lane == 0) {
            float* lo = logits_out + (size_t)t * NE;
            #pragma unroll
            for (int e = 0; e < NE; e++) { acc[e] += gb[e]; lo[e] = acc[e]; }
            // top-2 (strict > keeps lowest index on ties, matching jax.lax.top_k)
            float l0 = acc[0]; int e0 = 0;
            #pragma unroll
            for (int e = 1; e < NE; e++) if (acc[e] > l0) { l0 = acc[e]; e0 = e; }
            float l1 = -1e30f; int e1 = -1;
            #pragma unroll
            for (int e = 0; e < NE; e++) if (e != e0 && acc[e] > l1) { l1 = acc[e]; e1 = e; }
            float q = expf(l1 - l0);
            float wn0 = 1.f / (1.f + q);
            float wn1 = q / (1.f + q);
            int lp0 = atomicAdd(&lcount[e0], 1);
            int lp1 = atomicAdd(&lcount[e1], 1);
            s_e[ti * 2] = e0; s_lp[ti * 2] = lp0; s_wv[ti * 2] = wn0;
            s_e[ti * 2 + 1] = e1; s_lp[ti * 2 + 1] = lp1; s_wv[ti * 2 + 1] = wn1;
        }
    }
    __syncthreads();
    if (tid < NE) lbase[tid] = atomicAdd(&counts[tid], lcount[tid]);
    __syncthreads();
    if (tid < GATE_TPB * 2) {
        int e = s_e[tid];
        int gp = lbase[e] + s_lp[tid];
        int gi = (tbase + (tid >> 1)) * 2 + (tid & 1);
        pair_epos[gi] = (e << 28) | gp;
        pair_w[gi] = s_wv[tid];
    }
}

// ---------------- place: local scan of counts + pad-slot init + slot placement ----------------
__global__ __launch_bounds__(256) void place_kernel(
    const int* __restrict__ pair_epos, const float* __restrict__ pair_w,
    const int* __restrict__ counts, int* __restrict__ offsets_out,
    int* __restrict__ slot_token, float* __restrict__ slot_weight,
    int* __restrict__ tok2slot) {
    __shared__ int soff[NE + 1];
    __shared__ int scnt[NE];
    int tid = threadIdx.x;
    if (tid == 0) {
        int o = 0;
        soff[0] = 0;
        for (int e = 0; e < NE; e++) {
            int c = counts[e];
            scnt[e] = c;
            o += (c + 127) & ~127;
            soff[e + 1] = o;
        }
    }
    __syncthreads();
    if (blockIdx.x == 0 && tid <= NE) offsets_out[tid] = soff[tid];

    int gtid = blockIdx.x * 256 + tid;
    // init pad slots (gaps between counts[e] and the 128-padded boundary)
    {
        int gbase = 0;
        #pragma unroll
        for (int e = 0; e < NE; e++) {
            int gs = soff[e] + scnt[e];
            int gl = soff[e + 1] - gs;
            int idx = gtid - gbase;
            if (idx >= 0 && idx < gl) {
                slot_token[gs + idx] = 0;
                slot_weight[gs + idx] = 0.f;
            }
            gbase += gl;
        }
    }
    int p = gtid;
    if (p >= NPAIR) return;
    int ep = pair_epos[p];
    int e = ep >> 28;
    int pos = ep & 0x0FFFFFFF;
    int slot = soff[e] + pos;
    slot_token[slot] = p >> 1;
    slot_weight[slot] = pair_w[p];
    tok2slot[p] = slot;
}

// pipeline: 2-buffer LDS, BK=64, depth-1 prefetch, counted vmcnt, raw barriers.
#define BARRIER() asm volatile("s_barrier" ::: "memory")
#define WAIT_VM(n) asm volatile("s_waitcnt vmcnt(" #n ")" ::: "memory")
#define WAIT_LGKM0() do { asm volatile("s_waitcnt lgkmcnt(0)" ::: "memory"); \
                          __builtin_amdgcn_sched_barrier(0); } while (0)

// Swizzled LDS tile layout, 1024 chunks of 16B per 128x64 tile:
//   slot c holds global chunk (row = c>>3, kseg = (c&7) ^ (row&7)).
// Write: 8 threads per row cover the row's contiguous 128B (permuted) -> coalesced.
// Read: fragment (row, kseg = kk*4+lg) at slot row*8 + (kseg ^ (row&7));
//   kx = (kk*4+lg) ^ (lr&7): any aligned 8-lane window hits all 8 bank-groups once.
// Geometry (measured best, R13/R16): 512 thr / 8 waves (2m x 4n), 128x128 tile,
//   per-wave 64x32, acc[4][2] = 32 AGPR -> 4 waves/SIMD (16 waves/CU), 2 blocks/CU.

// ---------------- grouped GEMM 1: h = gelu(x @ W1 + b1) ----------------
// grid (8=expert, HID/128, 128): expert on blockIdx.x pins expert e -> XCD e (flat%8).
__global__ __launch_bounds__(512, 4) void gemm1_kernel(
    const unsigned short* __restrict__ xb, const unsigned short* __restrict__ W1t,
    const float* __restrict__ b1, const int* __restrict__ offsets,
    const int* __restrict__ slot_token, unsigned short* __restrict__ hbuf) {
    int e = blockIdx.x;
    int row_base = offsets[e];
    int rows = offsets[e + 1] - row_base;
    int m0 = blockIdx.z * 128;
    if (m0 >= rows) return;
    int n0 = blockIdx.y * 128;

    __shared__ unsigned short sA[2][128 * 64];
    __shared__ unsigned short sB[2][128 * 64];

    int tid = threadIdx.x;
    const unsigned short* w1e = W1t + (size_t)e * HID * DIMX;

    int srow = tid >> 3;                       // 0..63
    int kperm = (tid & 7) ^ (srow & 7);
    int tok0 = slot_token[row_base + m0 + srow];
    int tok1 = slot_token[row_base + m0 + srow + 64];
    const unsigned short* gA0 = xb + (size_t)tok0 * DIMX + kperm * 8;
    const unsigned short* gA1 = xb + (size_t)tok1 * DIMX + kperm * 8;
    const unsigned short* gB0 = w1e + (size_t)(n0 + srow) * DIMX + kperm * 8;
    const unsigned short* gB1 = w1e + (size_t)(n0 + srow + 64) * DIMX + kperm * 8;

#define STG1(b, k0) do { \
        gload16(gA0 + (k0), &sA[b][tid * 8]); \
        gload16(gA1 + (k0), &sA[b][(tid + 512) * 8]); \
        gload16(gB0 + (k0), &sB[b][tid * 8]); \
        gload16(gB1 + (k0), &sB[b][(tid + 512) * 8]); \
    } while (0)

    f32x4 acc[4][2] = {};
    int wid = tid >> 6; int wr = wid >> 2, wc = wid & 3;   // 2m x 4n waves
    int lane = tid & 63; int lr = lane & 15, lg = lane >> 4;
    int kx0 = lg ^ (lr & 7);                   // k-subtile 0; subtile 1 = kx0^4

#define CMP1(CUR) do { \
        _Pragma("unroll") \
        for (int kk = 0; kk < 2; kk++) { \
            int kxo = (kx0 ^ (kk * 4)) * 8; \
            s16x8 af[4], bfr[2]; \
            _Pragma("unroll") \
            for (int m = 0; m < 4; m++) af[m] = *(const s16x8*)&sA[CUR][(wr * 64 + m * 16 + lr) * 64 + kxo]; \
            _Pragma("unroll") \
            for (int n = 0; n < 2; n++) bfr[n] = *(const s16x8*)&sB[CUR][(wc * 32 + n * 16 + lr) * 64 + kxo]; \
            __builtin_amdgcn_s_setprio(1); \
            _Pragma("unroll") \
            for (int m = 0; m < 4; m++) { \
                _Pragma("unroll") \
                for (int n = 0; n < 2; n++) \
                    acc[m][n] = __builtin_amdgcn_mfma_f32_16x16x32_bf16(af[m], bfr[n], acc[m][n], 0, 0, 0); \
            } \
            __builtin_amdgcn_s_setprio(0); \
        } \
    } while (0)

    const int NT = DIMX / 64;
    STG1(0, 0);
    int cur = 0;
    for (int t = 0; t < NT - 1; ++t) {
        STG1(cur ^ 1, (t + 1) * 64);
        WAIT_VM(4);       // my 4 loads for tile t done; t+1's stay in flight
        BARRIER();
        CMP1(cur);
        WAIT_LGKM0();
        BARRIER();
        cur ^= 1;
    }
    WAIT_VM(0);
    BARRIER();
    CMP1(cur);
#undef STG1
#undef CMP1

    #pragma unroll
    for (int m = 0; m < 4; m++) {
        #pragma unroll
        for (int n = 0; n < 2; n++) {
            int col = n0 + wc * 32 + n * 16 + lr;
            float bias = b1[e * HID + col];
            #pragma unroll
            for (int i = 0; i < 4; i++) {
                int row = wr * 64 + m * 16 + lg * 4 + i;
                float v = gelu_fast(acc[m][n][i] + bias);
                hbuf[(size_t)(row_base + m0 + row) * HID + col] = f2bf(v);
            }
        }
    }
}

// ---------------- grouped GEMM 2: ybuf[slot] = w * (h @ W2 + b2), plain stores ----------------
__global__ __launch_bounds__(512, 4) void gemm2_kernel(
    const unsigned short* __restrict__ hbuf, const unsigned short* __restrict__ W2t,
    const float* __restrict__ b2, const int* __restrict__ offsets,
    const float* __restrict__ slot_weight, unsigned short* __restrict__ ybuf) {
    int e = blockIdx.x;
    int row_base = offsets[e];
    int rows = offsets[e + 1] - row_base;
    int m0 = blockIdx.z * 128;
    if (m0 >= rows) return;
    int n0 = blockIdx.y * 128;

    __shared__ unsigned short sA[2][128 * 64];
    __shared__ unsigned short sB[2][128 * 64];
    __shared__ float s_w[128];

    int tid = threadIdx.x;
    if (tid < 128) s_w[tid] = slot_weight[row_base + m0 + tid];

    const unsigned short* ha = hbuf + (size_t)(row_base + m0) * HID;
    const unsigned short* w2e = W2t + (size_t)e * DIMX * HID;

    int srow = tid >> 3;
    int kperm = (tid & 7) ^ (srow & 7);
    const unsigned short* gA0 = ha + (size_t)srow * HID + kperm * 8;
    const unsigned short* gA1 = ha + (size_t)(srow + 64) * HID + kperm * 8;
    const unsigned short* gB0 = w2e + (size_t)(n0 + srow) * HID + kperm * 8;
    const unsigned short* gB1 = w2e + (size_t)(n0 + srow + 64) * HID + kperm * 8;

#define STG2(b, k0) do { \
        gload16(gA0 + (k0), &sA[b][tid * 8]); \
        gload16(gA1 + (k0), &sA[b][(tid + 512) * 8]); \
        gload16(gB0 + (k0), &sB[b][tid * 8]); \
        gload16(gB1 + (k0), &sB[b][(tid + 512) * 8]); \
    } while (0)

    f32x4 acc[4][2] = {};
    int wid = tid >> 6; int wr = wid >> 2, wc = wid & 3;
    int lane = tid & 63; int lr = lane & 15, lg = lane >> 4;
    int kx0 = lg ^ (lr & 7);

#define CMP2(CUR) do { \
        _Pragma("unroll") \
        for (int kk = 0; kk < 2; kk++) { \
            int kxo = (kx0 ^ (kk * 4)) * 8; \
            s16x8 af[4], bfr[2]; \
            _Pragma("unroll") \
            for (int m = 0; m < 4; m++) af[m] = *(const s16x8*)&sA[CUR][(wr * 64 + m * 16 + lr) * 64 + kxo]; \
            _Pragma("unroll") \
            for (int n = 0; n < 2; n++) bfr[n] = *(const s16x8*)&sB[CUR][(wc * 32 + n * 16 + lr) * 64 + kxo]; \
            __builtin_amdgcn_s_setprio(1); \
            _Pragma("unroll") \
            for (int m = 0; m < 4; m++) { \
                _Pragma("unroll") \
                for (int n = 0; n < 2; n++) \
                    acc[m][n] = __builtin_amdgcn_mfma_f32_16x16x32_bf16(af[m], bfr[n], acc[m][n], 0, 0, 0); \
            } \
            __builtin_amdgcn_s_setprio(0); \
        } \
    } while (0)

    const int NT = HID / 64;
    STG2(0, 0);
    int cur = 0;
    for (int t = 0; t < NT - 1; ++t) {
        STG2(cur ^ 1, (t + 1) * 64);
        WAIT_VM(4);
        BARRIER();
        CMP2(cur);
        WAIT_LGKM0();
        BARRIER();
        cur ^= 1;
    }
    WAIT_VM(0);
    BARRIER();
    CMP2(cur);
#undef STG2
#undef CMP2

    #pragma unroll
    for (int m = 0; m < 4; m++) {
        #pragma unroll
        for (int n = 0; n < 2; n++) {
            int col = n0 + wc * 32 + n * 16 + lr;
            float bias = b2[e * DIMX + col];
            #pragma unroll
            for (int i = 0; i < 4; i++) {
                int row = wr * 64 + m * 16 + lg * 4 + i;
                float v = (acc[m][n][i] + bias) * s_w[row];
                ybuf[(size_t)(row_base + m0 + row) * DIMX + col] = f2bf(v);
            }
        }
    }
}

// ---------------- combine: out[t] = ybuf[slotA] + ybuf[slotB] ----------------
__global__ __launch_bounds__(256) void combine_kernel(
    const unsigned short* __restrict__ ybuf, const int* __restrict__ tok2slot,
    float* __restrict__ out) {
    int t = blockIdx.x;
    int d = threadIdx.x * 4;
    int sa = tok2slot[t * 2], sb = tok2slot[t * 2 + 1];
    ushort4 a = *(const ushort4*)&ybuf[(size_t)sa * DIMX + d];
    ushort4 b = *(const ushort4*)&ybuf[(size_t)sb * DIMX + d];
    float4 o;
    o.x = bf2f(a.x) + bf2f(b.x);
    o.y = bf2f(a.y) + bf2f(b.y);
    o.z = bf2f(a.z) + bf2f(b.z);
    o.w = bf2f(a.w) + bf2f(b.w);
    *(float4*)&out[(size_t)t * DIMX + d] = o;
}

extern "C" void kernel_launch(void* const* d_in, const int* in_sizes, int n_in,
                              void* d_out, int out_size, void* d_ws, size_t ws_size,
                              hipStream_t stream) {
    const float* x  = (const float*)d_in[0];
    const float* gw = (const float*)d_in[1];
    const float* gb = (const float*)d_in[2];
    const float* W1 = (const float*)d_in[3];
    const float* b1 = (const float*)d_in[4];
    const float* W2 = (const float*)d_in[5];
    const float* b2 = (const float*)d_in[6];
    float* out = (float*)d_out;
    float* logits = out + (size_t)T_TOK * DIMX;

    char* ws = (char*)d_ws;
    unsigned short* W2t = (unsigned short*)ws; ws += (size_t)NE * DIMX * HID * 2;
    // ybuf (P_PAD x DIMX bf16 = 35.7 MB) overlays [W1t | xb] (48 MB), both dead after gemm1.
    unsigned short* W1t = (unsigned short*)ws;
    unsigned short* ybuf = (unsigned short*)ws; ws += (size_t)NE * DIMX * HID * 2;
    unsigned short* xb = (unsigned short*)ws; ws += (size_t)T_TOK * DIMX * 2;
    unsigned short* hbuf = (unsigned short*)ws; ws += (size_t)P_PAD * HID * 2;
    int* counts = (int*)ws; ws += 256;
    int* offsets = (int*)ws; ws += 256;
    int* pair_epos = (int*)ws; ws += (size_t)NPAIR * 4;
    float* pair_w = (float*)ws; ws += (size_t)NPAIR * 4;
    int* slot_token = (int*)ws; ws += (size_t)P_PAD * 4;
    float* slot_weight = (float*)ws; ws += (size_t)P_PAD * 4;
    int* tok2slot = (int*)ws; ws += (size_t)NPAIR * 4;

    conv_transpose2_kernel<<<dim3(32, 32, 16), 256, 0, stream>>>(W1, W2, W1t, W2t, counts);
    gate_kernel<<<T_TOK / GATE_TPB, 256, 0, stream>>>(x, gw, gb, logits, counts, pair_epos,
                                                      pair_w, xb);
    place_kernel<<<NPAIR / 256, 256, 0, stream>>>(pair_epos, pair_w, counts, offsets,
                                                  slot_token, slot_weight, tok2slot);
    // expert on blockIdx.x (gridDim.x=8): flat_id % 8 == expert -> one XCD per expert.
    gemm1_kernel<<<dim3(NE, HID / 128, 128), 512, 0, stream>>>(xb, W1t, b1, offsets, slot_token, hbuf);
    gemm2_kernel<<<dim3(NE, DIMX / 128, 128), 512, 0, stream>>>(hbuf, W2t, b2, offsets, slot_weight, ybuf);
    combine_kernel<<<T_TOK, 256, 0, stream>>>(ybuf, tok2slot, out);
}

// Round 19
// 257.722 us; speedup vs baseline: 1.1017x; 1.0401x over previous
//
#include <hip/hip_runtime.h>
#include <math.h>

#define T_TOK 8192
#define DIMX 1024
#define NE 8
#define HID 2048
#define NPAIR (T_TOK * 2)
#define P_PAD (NPAIR + NE * 128)
#define GATE_TPB 32
#define NGATE (T_TOK / GATE_TPB)

typedef __attribute__((ext_vector_type(8))) short s16x8;
typedef __attribute__((ext_vector_type(4))) float f32x4;

static __device__ __forceinline__ unsigned short f2bf(float f) {
    union { float f; unsigned u; } v; v.f = f;
    unsigned r = v.u + 0x7FFFu + ((v.u >> 16) & 1u);
    return (unsigned short)(r >> 16);
}
static __device__ __forceinline__ float bf2f(unsigned short u) {
    union { unsigned u; float f; } v; v.u = (unsigned)u << 16; return v.f;
}

// gelu tanh approximation: v * sigmoid(1.5957691 * v * (1 + 0.044715 v^2))
static __device__ __forceinline__ float gelu_fast(float v) {
    float u2 = -1.5957691216057308f * v * (1.f + 0.044715f * v * v);
    return v * __builtin_amdgcn_rcpf(1.f + __expf(u2));
}

// async global->LDS, 16 bytes per lane. LDS dest must be wave-uniform base + lane*16.
static __device__ __forceinline__ void gload16(const unsigned short* g, unsigned short* l) {
    __builtin_amdgcn_global_load_lds(
        (const __attribute__((address_space(1))) unsigned int*)g,
        (__attribute__((address_space(3))) unsigned int*)l, 16, 0, 0);
}

// ---------------- prep: gate (blocks 0..255, dispatched first) + weight transpose ----------------
// Gate is atomic-free: emits per-block expert counts + block-local positions.
// Transpose: z<8 -> W1 [1024][2048], else W2 [2048][1024]; fp32 -> bf16 [E][C][R].
union PrepSmem {
    struct {
        float sgw[NE * DIMX];
        int lcount[NE];
        int s_e[GATE_TPB * 2];
        int s_lp[GATE_TPB * 2];
        float s_wv[GATE_TPB * 2];
    } g;
    float tile[64][65];
};

__global__ __launch_bounds__(256) void prep_kernel(
    const float* __restrict__ x, const float* __restrict__ gw, const float* __restrict__ gb,
    const float* __restrict__ W1, const float* __restrict__ W2,
    float* __restrict__ logits_out, int* __restrict__ blk_counts,
    int* __restrict__ pair_epos, float* __restrict__ pair_w,
    unsigned short* __restrict__ xb, unsigned short* __restrict__ W1t,
    unsigned short* __restrict__ W2t) {
    __shared__ PrepSmem sm;
    int bid = blockIdx.x;
    int tid = threadIdx.x;

    if (bid < NGATE) {
        // ---------------- gate ----------------
        for (int i = tid; i < NE * DIMX / 4; i += 256)
            ((float4*)sm.g.sgw)[i] = ((const float4*)gw)[i];
        if (tid < NE) sm.g.lcount[tid] = 0;
        __syncthreads();

        int wave = tid >> 6, lane = tid & 63;
        int tbase = bid * GATE_TPB;
        for (int r = 0; r < GATE_TPB / 4; ++r) {
            int ti = wave * (GATE_TPB / 4) + r;
            int t = tbase + ti;
            const float* xr = x + (size_t)t * DIMX;
            float acc[NE] = {};
            #pragma unroll
            for (int i = 0; i < DIMX / 256; i++) {
                float4 xv = *(const float4*)&xr[i * 256 + lane * 4];
                unsigned short rb[4] = { f2bf(xv.x), f2bf(xv.y), f2bf(xv.z), f2bf(xv.w) };
                *(uint2*)&xb[(size_t)t * DIMX + i * 256 + lane * 4] = *(const uint2*)&rb[0];
                #pragma unroll
                for (int e = 0; e < NE; e++) {
                    float4 wv = *(const float4*)&sm.g.sgw[e * DIMX + i * 256 + lane * 4];
                    acc[e] += xv.x * wv.x + xv.y * wv.y + xv.z * wv.z + xv.w * wv.w;
                }
            }
            #pragma unroll
            for (int e = 0; e < NE; e++) {
                #pragma unroll
                for (int off = 32; off; off >>= 1) acc[e] += __shfl_xor(acc[e], off);
            }
            if (lane == 0) {
                float* lo = logits_out + (size_t)t * NE;
                #pragma unroll
                for (int e = 0; e < NE; e++) { acc[e] += gb[e]; lo[e] = acc[e]; }
                // top-2 (strict > keeps lowest index on ties, matching jax.lax.top_k)
                float l0 = acc[0]; int e0 = 0;
                #pragma unroll
                for (int e = 1; e < NE; e++) if (acc[e] > l0) { l0 = acc[e]; e0 = e; }
                float l1 = -1e30f; int e1 = -1;
                #pragma unroll
                for (int e = 0; e < NE; e++) if (e != e0 && acc[e] > l1) { l1 = acc[e]; e1 = e; }
                float q = expf(l1 - l0);
                float wn0 = 1.f / (1.f + q);
                float wn1 = q / (1.f + q);
                int lp0 = atomicAdd(&sm.g.lcount[e0], 1);
                int lp1 = atomicAdd(&sm.g.lcount[e1], 1);
                sm.g.s_e[ti * 2] = e0; sm.g.s_lp[ti * 2] = lp0; sm.g.s_wv[ti * 2] = wn0;
                sm.g.s_e[ti * 2 + 1] = e1; sm.g.s_lp[ti * 2 + 1] = lp1; sm.g.s_wv[ti * 2 + 1] = wn1;
            }
        }
        __syncthreads();
        if (tid < NE) blk_counts[bid * NE + tid] = sm.g.lcount[tid];
        if (tid < GATE_TPB * 2) {
            int gi = (tbase + (tid >> 1)) * 2 + (tid & 1);
            pair_epos[gi] = (sm.g.s_e[tid] << 28) | sm.g.s_lp[tid];
            pair_w[gi] = sm.g.s_wv[tid];
        }
    } else {
        // ---------------- transpose ----------------
        int zb = bid - NGATE;
        int z = zb >> 10;
        int rem = zb & 1023;
        int by = rem >> 5, bx = rem & 31;
        int e = z & 7;
        const float* srcb; unsigned short* dstb; int R, C;
        if (z < 8) { srcb = W1; dstb = W1t; R = DIMX; C = HID; }
        else       { srcb = W2; dstb = W2t; R = HID; C = DIMX; }
        int r0 = by * 64, c0 = bx * 64;
        if (r0 >= R || c0 >= C) return;
        const float* s = srcb + (size_t)e * R * C;
        unsigned short* d = dstb + (size_t)e * R * C;
        int lr = tid >> 4, lc4 = (tid & 15) * 4;  // 16 rows per pass x 16 float4
        #pragma unroll
        for (int it = 0; it < 4; it++) {
            float4 v = *(const float4*)&s[(size_t)(r0 + it * 16 + lr) * C + c0 + lc4];
            sm.tile[it * 16 + lr][lc4 + 0] = v.x;
            sm.tile[it * 16 + lr][lc4 + 1] = v.y;
            sm.tile[it * 16 + lr][lc4 + 2] = v.z;
            sm.tile[it * 16 + lr][lc4 + 3] = v.w;
        }
        __syncthreads();
        int cc = tid >> 3, rch = (tid & 7) * 8;  // 32 dst rows per pass x 8 chunks of 8
        #pragma unroll
        for (int it = 0; it < 2; it++) {
            int c = it * 32 + cc;
            unsigned short r[8];
            #pragma unroll
            for (int j = 0; j < 8; j++) r[j] = f2bf(sm.tile[rch + j][c]);
            *(uint4*)&d[(size_t)(c0 + c) * R + r0 + rch] = *(const uint4*)&r[0];
        }
    }
}

// ---------------- place: per-expert scan of blk_counts + pad init + slot placement ----------------
__global__ __launch_bounds__(256) void place_kernel(
    const int* __restrict__ pair_epos, const float* __restrict__ pair_w,
    const int* __restrict__ blk_counts, int* __restrict__ offsets_out,
    int* __restrict__ slot_token, float* __restrict__ slot_weight,
    int* __restrict__ tok2slot) {
    __shared__ int scnt[NGATE][NE];   // 8KB
    __shared__ int sbase[NGATE][NE];  // 8KB (exclusive prefix per gate block)
    __shared__ int soff[NE + 1];
    __shared__ int stot[NE];
    int tid = threadIdx.x;
    #pragma unroll
    for (int e = 0; e < NE; e++) scnt[tid][e] = blk_counts[tid * NE + e];
    __syncthreads();
    // per-expert scan: expert e = tid>>5 handled by a 32-lane segment; lane j sums 8 blocks
    {
        int e = tid >> 5, j = tid & 31;
        int cs[8];
        int part = 0;
        #pragma unroll
        for (int i = 0; i < 8; i++) { cs[i] = part; part += scnt[j * 8 + i][e]; }
        int inc = part;
        #pragma unroll
        for (int d = 1; d < 32; d <<= 1) {
            int up = __shfl_up(inc, d, 32);
            if (j >= d) inc += up;
        }
        int excl = inc - part;
        #pragma unroll
        for (int i = 0; i < 8; i++) sbase[j * 8 + i][e] = excl + cs[i];
        if (j == 31) stot[e] = inc;
    }
    __syncthreads();
    if (tid == 0) {
        int o = 0;
        soff[0] = 0;
        for (int k = 0; k < NE; k++) { o += (stot[k] + 127) & ~127; soff[k + 1] = o; }
    }
    __syncthreads();
    if (blockIdx.x == 0 && tid <= NE) offsets_out[tid] = soff[tid];

    int gtid = blockIdx.x * 256 + tid;
    // init pad slots (gaps between stot[e] and the 128-padded boundary)
    {
        int gbase = 0;
        #pragma unroll
        for (int k = 0; k < NE; k++) {
            int gs = soff[k] + stot[k];
            int gl = soff[k + 1] - gs;
            int idx = gtid - gbase;
            if (idx >= 0 && idx < gl) {
                slot_token[gs + idx] = 0;
                slot_weight[gs + idx] = 0.f;
            }
            gbase += gl;
        }
    }
    int p = gtid;  // grid is exactly NPAIR/256 blocks
    int ep = pair_epos[p];
    int pe = ep >> 28;
    int lp = ep & 0x0FFFFFFF;
    int g = p >> 6;  // gate block that produced this pair (64 pairs per gate block)
    int slot = soff[pe] + sbase[g][pe] + lp;
    slot_token[slot] = p >> 1;
    slot_weight[slot] = pair_w[p];
    tok2slot[p] = slot;
}

// pipeline: 2-buffer LDS, BK=64, depth-1 prefetch, counted vmcnt, raw barriers.
#define BARRIER() asm volatile("s_barrier" ::: "memory")
#define WAIT_VM(n) asm volatile("s_waitcnt vmcnt(" #n ")" ::: "memory")
#define WAIT_LGKM0() do { asm volatile("s_waitcnt lgkmcnt(0)" ::: "memory"); \
                          __builtin_amdgcn_sched_barrier(0); } while (0)

// Swizzled LDS tile layout, 1024 chunks of 16B per 128x64 tile:
//   slot c holds global chunk (row = c>>3, kseg = (c&7) ^ (row&7)).
// Write: 8 threads per row cover the row's contiguous 128B (permuted) -> coalesced.
// Read: fragment (row, kseg = kk*4+lg) at slot row*8 + (kseg ^ (row&7));
//   kx = (kk*4+lg) ^ (lr&7): any aligned 8-lane window hits all 8 bank-groups once.
// Geometry (measured best, R13/R16/R18): 512 thr / 8 waves (2m x 4n), 128x128 tile,
//   per-wave 64x32, acc[4][2] = 32 AGPR -> 4 waves/SIMD (16 waves/CU), 2 blocks/CU.

// ---------------- grouped GEMM 1: h = gelu(x @ W1 + b1) ----------------
// grid (8=expert, HID/128, 128): expert on blockIdx.x pins expert e -> XCD e (flat%8).
__global__ __launch_bounds__(512, 4) void gemm1_kernel(
    const unsigned short* __restrict__ xb, const unsigned short* __restrict__ W1t,
    const float* __restrict__ b1, const int* __restrict__ offsets,
    const int* __restrict__ slot_token, unsigned short* __restrict__ hbuf) {
    int e = blockIdx.x;
    int row_base = offsets[e];
    int rows = offsets[e + 1] - row_base;
    int m0 = blockIdx.z * 128;
    if (m0 >= rows) return;
    int n0 = blockIdx.y * 128;

    __shared__ unsigned short sA[2][128 * 64];
    __shared__ unsigned short sB[2][128 * 64];

    int tid = threadIdx.x;
    const unsigned short* w1e = W1t + (size_t)e * HID * DIMX;

    int srow = tid >> 3;                       // 0..63
    int kperm = (tid & 7) ^ (srow & 7);
    int tok0 = slot_token[row_base + m0 + srow];
    int tok1 = slot_token[row_base + m0 + srow + 64];
    const unsigned short* gA0 = xb + (size_t)tok0 * DIMX + kperm * 8;
    const unsigned short* gA1 = xb + (size_t)tok1 * DIMX + kperm * 8;
    const unsigned short* gB0 = w1e + (size_t)(n0 + srow) * DIMX + kperm * 8;
    const unsigned short* gB1 = w1e + (size_t)(n0 + srow + 64) * DIMX + kperm * 8;

#define STG1(b, k0) do { \
        gload16(gA0 + (k0), &sA[b][tid * 8]); \
        gload16(gA1 + (k0), &sA[b][(tid + 512) * 8]); \
        gload16(gB0 + (k0), &sB[b][tid * 8]); \
        gload16(gB1 + (k0), &sB[b][(tid + 512) * 8]); \
    } while (0)

    f32x4 acc[4][2] = {};
    int wid = tid >> 6; int wr = wid >> 2, wc = wid & 3;   // 2m x 4n waves
    int lane = tid & 63; int lr = lane & 15, lg = lane >> 4;
    int kx0 = lg ^ (lr & 7);                   // k-subtile 0; subtile 1 = kx0^4

#define CMP1(CUR) do { \
        _Pragma("unroll") \
        for (int kk = 0; kk < 2; kk++) { \
            int kxo = (kx0 ^ (kk * 4)) * 8; \
            s16x8 af[4], bfr[2]; \
            _Pragma("unroll") \
            for (int m = 0; m < 4; m++) af[m] = *(const s16x8*)&sA[CUR][(wr * 64 + m * 16 + lr) * 64 + kxo]; \
            _Pragma("unroll") \
            for (int n = 0; n < 2; n++) bfr[n] = *(const s16x8*)&sB[CUR][(wc * 32 + n * 16 + lr) * 64 + kxo]; \
            __builtin_amdgcn_s_setprio(1); \
            _Pragma("unroll") \
            for (int m = 0; m < 4; m++) { \
                _Pragma("unroll") \
                for (int n = 0; n < 2; n++) \
                    acc[m][n] = __builtin_amdgcn_mfma_f32_16x16x32_bf16(af[m], bfr[n], acc[m][n], 0, 0, 0); \
            } \
            __builtin_amdgcn_s_setprio(0); \
        } \
    } while (0)

    const int NT = DIMX / 64;
    STG1(0, 0);
    int cur = 0;
    for (int t = 0; t < NT - 1; ++t) {
        STG1(cur ^ 1, (t + 1) * 64);
        WAIT_VM(4);       // my 4 loads for tile t done; t+1's stay in flight
        BARRIER();
        CMP1(cur);
        WAIT_LGKM0();
        BARRIER();
        cur ^= 1;
    }
    WAIT_VM(0);
    BARRIER();
    CMP1(cur);
#undef STG1
#undef CMP1

    #pragma unroll
    for (int m = 0; m < 4; m++) {
        #pragma unroll
        for (int n = 0; n < 2; n++) {
            int col = n0 + wc * 32 + n * 16 + lr;
            float bias = b1[e * HID + col];
            #pragma unroll
            for (int i = 0; i < 4; i++) {
                int row = wr * 64 + m * 16 + lg * 4 + i;
                float v = gelu_fast(acc[m][n][i] + bias);
                hbuf[(size_t)(row_base + m0 + row) * HID + col] = f2bf(v);
            }
        }
    }
}

// ---------------- grouped GEMM 2: ybuf[slot] = w * (h @ W2 + b2), plain stores ----------------
__global__ __launch_bounds__(512, 4) void gemm2_kernel(
    const unsigned short* __restrict__ hbuf, const unsigned short* __restrict__ W2t,
    const float* __restrict__ b2, const int* __restrict__ offsets,
    const float* __restrict__ slot_weight, unsigned short* __restrict__ ybuf) {
    int e = blockIdx.x;
    int row_base = offsets[e];
    int rows = offsets[e + 1] - row_base;
    int m0 = blockIdx.z * 128;
    if (m0 >= rows) return;
    int n0 = blockIdx.y * 128;

    __shared__ unsigned short sA[2][128 * 64];
    __shared__ unsigned short sB[2][128 * 64];
    __shared__ float s_w[128];

    int tid = threadIdx.x;
    if (tid < 128) s_w[tid] = slot_weight[row_base + m0 + tid];

    const unsigned short* ha = hbuf + (size_t)(row_base + m0) * HID;
    const unsigned short* w2e = W2t + (size_t)e * DIMX * HID;

    int srow = tid >> 3;
    int kperm = (tid & 7) ^ (srow & 7);
    const unsigned short* gA0 = ha + (size_t)srow * HID + kperm * 8;
    const unsigned short* gA1 = ha + (size_t)(srow + 64) * HID + kperm * 8;
    const unsigned short* gB0 = w2e + (size_t)(n0 + srow) * HID + kperm * 8;
    const unsigned short* gB1 = w2e + (size_t)(n0 + srow + 64) * HID + kperm * 8;

#define STG2(b, k0) do { \
        gload16(gA0 + (k0), &sA[b][tid * 8]); \
        gload16(gA1 + (k0), &sA[b][(tid + 512) * 8]); \
        gload16(gB0 + (k0), &sB[b][tid * 8]); \
        gload16(gB1 + (k0), &sB[b][(tid + 512) * 8]); \
    } while (0)

    f32x4 acc[4][2] = {};
    int wid = tid >> 6; int wr = wid >> 2, wc = wid & 3;
    int lane = tid & 63; int lr = lane & 15, lg = lane >> 4;
    int kx0 = lg ^ (lr & 7);

#define CMP2(CUR) do { \
        _Pragma("unroll") \
        for (int kk = 0; kk < 2; kk++) { \
            int kxo = (kx0 ^ (kk * 4)) * 8; \
            s16x8 af[4], bfr[2]; \
            _Pragma("unroll") \
            for (int m = 0; m < 4; m++) af[m] = *(const s16x8*)&sA[CUR][(wr * 64 + m * 16 + lr) * 64 + kxo]; \
            _Pragma("unroll") \
            for (int n = 0; n < 2; n++) bfr[n] = *(const s16x8*)&sB[CUR][(wc * 32 + n * 16 + lr) * 64 + kxo]; \
            __builtin_amdgcn_s_setprio(1); \
            _Pragma("unroll") \
            for (int m = 0; m < 4; m++) { \
                _Pragma("unroll") \
                for (int n = 0; n < 2; n++) \
                    acc[m][n] = __builtin_amdgcn_mfma_f32_16x16x32_bf16(af[m], bfr[n], acc[m][n], 0, 0, 0); \
            } \
            __builtin_amdgcn_s_setprio(0); \
        } \
    } while (0)

    const int NT = HID / 64;
    STG2(0, 0);
    int cur = 0;
    for (int t = 0; t < NT - 1; ++t) {
        STG2(cur ^ 1, (t + 1) * 64);
        WAIT_VM(4);
        BARRIER();
        CMP2(cur);
        WAIT_LGKM0();
        BARRIER();
        cur ^= 1;
    }
    WAIT_VM(0);
    BARRIER();
    CMP2(cur);
#undef STG2
#undef CMP2

    #pragma unroll
    for (int m = 0; m < 4; m++) {
        #pragma unroll
        for (int n = 0; n < 2; n++) {
            int col = n0 + wc * 32 + n * 16 + lr;
            float bias = b2[e * DIMX + col];
            #pragma unroll
            for (int i = 0; i < 4; i++) {
                int row = wr * 64 + m * 16 + lg * 4 + i;
                float v = (acc[m][n][i] + bias) * s_w[row];
                ybuf[(size_t)(row_base + m0 + row) * DIMX + col] = f2bf(v);
            }
        }
    }
}

// ---------------- combine: out[t] = ybuf[slotA] + ybuf[slotB] ----------------
__global__ __launch_bounds__(256) void combine_kernel(
    const unsigned short* __restrict__ ybuf, const int* __restrict__ tok2slot,
    float* __restrict__ out) {
    int t = blockIdx.x;
    int d = threadIdx.x * 4;
    int sa = tok2slot[t * 2], sb = tok2slot[t * 2 + 1];
    ushort4 a = *(const ushort4*)&ybuf[(size_t)sa * DIMX + d];
    ushort4 b = *(const ushort4*)&ybuf[(size_t)sb * DIMX + d];
    float4 o;
    o.x = bf2f(a.x) + bf2f(b.x);
    o.y = bf2f(a.y) + bf2f(b.y);
    o.z = bf2f(a.z) + bf2f(b.z);
    o.w = bf2f(a.w) + bf2f(b.w);
    *(float4*)&out[(size_t)t * DIMX + d] = o;
}

extern "C" void kernel_launch(void* const* d_in, const int* in_sizes, int n_in,
                              void* d_out, int out_size, void* d_ws, size_t ws_size,
                              hipStream_t stream) {
    const float* x  = (const float*)d_in[0];
    const float* gw = (const float*)d_in[1];
    const float* gb = (const float*)d_in[2];
    const float* W1 = (const float*)d_in[3];
    const float* b1 = (const float*)d_in[4];
    const float* W2 = (const float*)d_in[5];
    const float* b2 = (const float*)d_in[6];
    float* out = (float*)d_out;
    float* logits = out + (size_t)T_TOK * DIMX;

    char* ws = (char*)d_ws;
    unsigned short* W2t = (unsigned short*)ws; ws += (size_t)NE * DIMX * HID * 2;
    // ybuf (P_PAD x DIMX bf16 = 35.7 MB) overlays [W1t | xb] (48 MB), both dead after gemm1.
    unsigned short* W1t = (unsigned short*)ws;
    unsigned short* ybuf = (unsigned short*)ws; ws += (size_t)NE * DIMX * HID * 2;
    unsigned short* xb = (unsigned short*)ws; ws += (size_t)T_TOK * DIMX * 2;
    unsigned short* hbuf = (unsigned short*)ws; ws += (size_t)P_PAD * HID * 2;
    int* blk_counts = (int*)ws; ws += (size_t)NGATE * NE * 4;
    int* offsets = (int*)ws; ws += 256;
    int* pair_epos = (int*)ws; ws += (size_t)NPAIR * 4;
    float* pair_w = (float*)ws; ws += (size_t)NPAIR * 4;
    int* slot_token = (int*)ws; ws += (size_t)P_PAD * 4;
    float* slot_weight = (float*)ws; ws += (size_t)P_PAD * 4;
    int* tok2slot = (int*)ws; ws += (size_t)NPAIR * 4;

    // gate blocks (0..255) dispatch first and overlap with the 16384 transpose blocks.
    prep_kernel<<<NGATE + 16384, 256, 0, stream>>>(x, gw, gb, W1, W2, logits, blk_counts,
                                                   pair_epos, pair_w, xb, W1t, W2t);
    place_kernel<<<NPAIR / 256, 256, 0, stream>>>(pair_epos, pair_w, blk_counts, offsets,
                                                  slot_token, slot_weight, tok2slot);
    // expert on blockIdx.x (gridDim.x=8): flat_id % 8 == expert -> one XCD per expert.
    gemm1_kernel<<<dim3(NE, HID / 128, 128), 512, 0, stream>>>(xb, W1t, b1, offsets, slot_token, hbuf);
    gemm2_kernel<<<dim3(NE, DIMX / 128, 128), 512, 0, stream>>>(hbuf, W2t, b2, offsets, slot_weight, ybuf);
    combine_kernel<<<T_TOK, 256, 0, stream>>>(ybuf, tok2slot, out);
}